// Round 16
// baseline (86.542 us; speedup 1.0000x reference)
//
#include <hip/hip_runtime.h>
#include <hip/hip_bf16.h>
#include <stdint.h>

// Fused NCA step via MATRIX CORES — bf16-tile build for max occupancy.
// perception(4 fixed 3x3, wrap) -> 1x1 conv 32->16 +b+ReLU -> 1x1 conv 16->8
// -> x + y*mask.
// R16: R14/R15 showed latency-bound at 4 waves/SIMD (VALUBusy 46-50%, equal
// dur despite VALU cuts); fp32 tile (>=64KB) caps at 2 blocks/CU. Staging the
// tile as bf16 (34 KB) fits 4 blocks/CU = 32 waves/CU (2x latency hiding):
//  - reg-stage: float4 global -> __float22bfloat162_rn (HW cvt_pk, RNE,
//    R15-verified) -> ds_write. No global_load_lds (conversion needed).
//  - column extract: 2 adjacent u32 reads + shift/and + per-lane-constant
//    cndmask (verified primitives only; parity of px is per-lane fixed).
//  - residual x read bf16 from LDS (+~0.011 abs err; budget 0.031+0.02<0.114).
// Everything else byte-identical to R15 (fragments, folding, conv1 hi/lo W
// split 2xMFMA, conv2 zero-padded K=32 MFMA, direct mask loads, epilogue).

constexpr int B = 16, C = 8, H = 512, W = 512, HID = 16;
constexpr int HW = H * W;

// LDS: bf16 tile. Row = 528 bf16 = 264 u32 (2080B data + halo + pad).
// data col c at bf16 idx c+4; left halo idx3 = col 511; right idx516 = col 0.
constexpr int ROWU = 264;             // u32 per row; %32 = 8 -> rows bank-offset
constexpr int CHB  = 4 * ROWU + 8;    // 1064 u32 per channel; %32 = 8
constexpr int LDSU = 8 * CHB;         // 8512 u32 = 34048 B -> 4 blocks/CU

typedef __attribute__((ext_vector_type(8))) short bf16x8;
typedef __attribute__((ext_vector_type(4))) float f32x4;

__device__ __host__ inline uint32_t bf16rne(float f) {   // result in low 16
    const uint32_t u = __float_as_uint(f);
    return (u + 0x7fffu + ((u >> 16) & 1u)) >> 16;
}
__device__ inline float bf16tof(uint32_t hs) { return __uint_as_float(hs << 16); }

// pack two floats to {bf16 lo, bf16 hi} via HW cvt_pk (RNE)
__device__ inline uint32_t pk2(float a, float b) {
    union { __hip_bfloat162 h; uint32_t u; } r;
    r.h = __float22bfloat162_rn(make_float2(a, b));
    return r.u;
}

// d_ws layout (u32 units):
//  [0..255]   W1eff hi A-frag: lane t holds elems j=0..7 of (row=t&15, grp=t>>4)
//  [256..511] W1eff lo A-frag
//  [512..767] W2 A-frag, K=32 zero-padded: j<4 -> w2[och=t&15][(t>>4)*4+j]
//             (0 for och>=8), j>=4 -> 0
//  [768..783] bias (f32)
__global__ void repack(const float* __restrict__ w1w,
                       const float* __restrict__ w1b,
                       const float* __restrict__ w2w,
                       float* __restrict__ wdf) {
    uint32_t* wd = (uint32_t*)wdf;
    const int t = threadIdx.x;
    if (t >= 64) return;
    const int h = t & 15, kg = t >> 4;
    uint32_t whi[4] = {0, 0, 0, 0}, wlo[4] = {0, 0, 0, 0}, w2f[4] = {0, 0, 0, 0};
    for (int j = 0; j < 8; ++j) {
        const int k = kg * 8 + j, ch = k >> 2, f = k & 3;
        const float* wr = w1w + h * 32 + ch * 4;
        // fold perception scales + lap's -ident into W1
        const float we = (f == 0) ? (wr[0] - wr[3])
                       : (f == 3) ? wr[3] * 0.0625f
                                  : wr[f] * 0.125f;
        const uint32_t hs = bf16rne(we);
        const uint32_t ls = bf16rne(we - bf16tof(hs));
        whi[j >> 1] |= hs << (16 * (j & 1));
        wlo[j >> 1] |= ls << (16 * (j & 1));
    }
    for (int j = 0; j < 4; ++j) {        // conv2 frag: j>=4 stays zero
        const float v = (h < 8) ? w2w[h * 16 + kg * 4 + j] : 0.0f;
        w2f[j >> 1] |= bf16rne(v) << (16 * (j & 1));
    }
    for (int q = 0; q < 4; ++q) {
        wd[t * 4 + q]       = whi[q];
        wd[256 + t * 4 + q] = wlo[q];
        wd[512 + t * 4 + q] = w2f[q];
    }
    if (t < 16) wdf[768 + t] = w1b[t];
}

__global__ __launch_bounds__(512, 8) void nca_step_kernel(
    const float* __restrict__ x,
    const int*   __restrict__ mask,
    float*       __restrict__ out,
    const float* __restrict__ wdf)
{
    __shared__ uint32_t S32[LDSU];
    uint16_t* Sh = (uint16_t*)S32;

    // block = one row PAIR; XCD-bijective swizzle (4096 = 8 * 512)
    const int bid = blockIdx.x;
    const int l   = (bid & 7) * 512 + (bid >> 3);
    const int b   = l >> 8;
    const int y0  = (l & 255) << 1;

    const int tid  = threadIdx.x;
    const int lane = tid & 63;
    const int wv   = tid >> 6;            // wave 0..7

    const float* xb = x + (size_t)b * C * HW;
    const int*   mb = mask + (size_t)b * HW;

    const int rel = wv >> 2;              // 0: row y0, 1: row y1
    const int y   = y0 + rel;
    const int grp = lane >> 4;            // lane-group: channels 2grp, 2grp+1
    const int p   = lane & 15;            // px within group
    const int chA = grp * 2;

    // ---- reg-stage: f32 global -> bf16 LDS (2 rounds of 4 channels) ----
    // wave wv owns (rs = (wv>>1)&3, hf = wv&1) for all 8 channels.
    {
        const int rs   = (wv >> 1) & 3;
        const int hf   = wv & 1;
        const int grow = (y0 - 1 + rs) & (H - 1);
        const int gbase = grow * W + hf * 256 + lane * 4;
        const int lbase = rs * ROWU + 2 + hf * 128 + lane * 2;
        const float4 v0 = *(const float4*)(xb + 0 * HW + gbase);
        const float4 v1 = *(const float4*)(xb + 1 * HW + gbase);
        const float4 v2 = *(const float4*)(xb + 2 * HW + gbase);
        const float4 v3 = *(const float4*)(xb + 3 * HW + gbase);
        S32[0 * CHB + lbase] = pk2(v0.x, v0.y);
        S32[0 * CHB + lbase + 1] = pk2(v0.z, v0.w);
        S32[1 * CHB + lbase] = pk2(v1.x, v1.y);
        S32[1 * CHB + lbase + 1] = pk2(v1.z, v1.w);
        S32[2 * CHB + lbase] = pk2(v2.x, v2.y);
        S32[2 * CHB + lbase + 1] = pk2(v2.z, v2.w);
        S32[3 * CHB + lbase] = pk2(v3.x, v3.y);
        S32[3 * CHB + lbase + 1] = pk2(v3.z, v3.w);
        const float4 v4 = *(const float4*)(xb + 4 * HW + gbase);
        const float4 v5 = *(const float4*)(xb + 5 * HW + gbase);
        const float4 v6 = *(const float4*)(xb + 6 * HW + gbase);
        const float4 v7 = *(const float4*)(xb + 7 * HW + gbase);
        S32[4 * CHB + lbase] = pk2(v4.x, v4.y);
        S32[4 * CHB + lbase + 1] = pk2(v4.z, v4.w);
        S32[5 * CHB + lbase] = pk2(v5.x, v5.y);
        S32[5 * CHB + lbase + 1] = pk2(v5.z, v5.w);
        S32[6 * CHB + lbase] = pk2(v6.x, v6.y);
        S32[6 * CHB + lbase + 1] = pk2(v6.z, v6.w);
        S32[7 * CHB + lbase] = pk2(v7.x, v7.y);
        S32[7 * CHB + lbase + 1] = pk2(v7.z, v7.w);
    }

    // fragments + mask: issued here, latency overlaps the barrier wait
    union { uint4 u; bf16x8 v; } whiU, wloU, w2U;
    whiU.u = ((const uint4*)wdf)[lane];
    wloU.u = ((const uint4*)wdf)[64 + lane];
    w2U.u  = ((const uint4*)wdf)[128 + lane];
    const f32x4 bias4 = ((const f32x4*)(wdf + 768))[lane >> 4];
    int msk[8];
#pragma unroll
    for (int i = 0; i < 8; ++i)
        msk[i] = mb[y * W + ((wv & 3) + 4 * i) * 16 + p];

    __syncthreads();                      // LDS writes + all loads done
    if (tid < 64) {                       // halo fill (wrap columns), bf16
        const int r = tid >> 1;
        uint16_t* rb = Sh + ((r >> 2) * CHB + (r & 3) * ROWU) * 2;
        if (tid & 1) rb[516] = rb[4];     // right halo = col 0
        else         rb[3]   = rb[515];   // left halo  = col 511
    }
    __syncthreads();

    float* ob = out + (size_t)b * C * HW;

    // per-lane-constant column-parity predicate: ci = px+3, px parity = p
    const bool ev = (p & 1) != 0;         // ci even <=> p odd

    // extract 3 f32 cols (bf16<<16) from two adjacent u32s, parity-selected
#define EXT3(aa0, aa1, aa2, ux, uy) do {                                   \
    const uint32_t xl_ = (ux) << 16, xh_ = (ux) & 0xFFFF0000u;             \
    const uint32_t yl_ = (uy) << 16, yh_ = (uy) & 0xFFFF0000u;             \
    aa0 = __uint_as_float(ev ? xl_ : xh_);                                 \
    aa1 = __uint_as_float(ev ? xh_ : yl_);                                 \
    aa2 = __uint_as_float(ev ? yl_ : yh_); } while (0)

    // ---- compute: wave wv -> row y0+rel, px groups (wv&3)+4i ----
#pragma unroll
    for (int i = 0; i < 8; ++i) {
        const int g  = (wv & 3) + i * 4;
        const int px = g * 16 + p;
        const int eu = (px + 3) >> 1;     // u32 idx of (col px-1)'s pair

        // features in fragment element order: j=0..3 ch=chA, j=4..7 ch=chA+1,
        // each {ident, sx_raw, sy_raw, lap_raw} (scales folded into W1)
        float f_[8];
#pragma unroll
        for (int cc = 0; cc < 2; ++cc) {
            const uint32_t* Rc = S32 + (chA + cc) * CHB + rel * ROWU + eu;
            const uint32_t ux0 = Rc[0],            uy0 = Rc[1];
            const uint32_t ux1 = Rc[ROWU],         uy1 = Rc[ROWU + 1];
            const uint32_t ux2 = Rc[2 * ROWU],     uy2 = Rc[2 * ROWU + 1];
            float a0, a1, a2, b0, b1, b2, c0, c1, c2;
            EXT3(a0, a1, a2, ux0, uy0);
            EXT3(b0, b1, b2, ux1, uy1);
            EXT3(c0, c1, c2, ux2, uy2);
            const float s0 = fmaf(2.f, b0, a0 + c0);
            const float s1 = fmaf(2.f, b1, a1 + c1);
            const float s2 = fmaf(2.f, b2, a2 + c2);
            const float d0 = c0 - a0, d1 = c1 - a1, d2 = c2 - a2;
            f_[cc * 4 + 0] = b1;
            f_[cc * 4 + 1] = s2 - s0;
            f_[cc * 4 + 2] = fmaf(2.f, d1, d0 + d2);
            f_[cc * 4 + 3] = fmaf(2.f, s1, s0 + s2);
        }

        // single-bf16 feature fragment: 4x HW cvt_pk
        union { uint32_t u[4]; bf16x8 v; } bh = {{
            pk2(f_[0], f_[1]), pk2(f_[2], f_[3]),
            pk2(f_[4], f_[5]), pk2(f_[6], f_[7])}};

        // conv1: W*F = (Whi + Wlo)*F   (W split exact; bias preloaded in C)
        f32x4 acc = bias4;
        acc = __builtin_amdgcn_mfma_f32_16x16x32_bf16(whiU.v, bh.v, acc, 0, 0, 0);
        acc = __builtin_amdgcn_mfma_f32_16x16x32_bf16(wloU.v, bh.v, acc, 0, 0, 0);

        // conv2 via the SAME verified K=32 builtin, zero-padded fragments
        union { uint32_t u[4]; bf16x8 v; } b2 = {{
            pk2(fmaxf(acc[0], 0.f), fmaxf(acc[1], 0.f)),
            pk2(fmaxf(acc[2], 0.f), fmaxf(acc[3], 0.f)), 0, 0}};
        f32x4 d2 = {0.f, 0.f, 0.f, 0.f};
        d2 = __builtin_amdgcn_mfma_f32_16x16x32_bf16(w2U.v, b2.v, d2, 0, 0, 0);

        // epilogue: lanes 0..31 hold och=(lane>>4)*4+r (rows 8..15 are pad)
        if (lane < 32) {
            const float mfv = (float)msk[i];
            const int och0 = grp * 4;
            float* op = ob + y * W + px;
#pragma unroll
            for (int r = 0; r < 4; ++r) {
                const uint32_t xr =
                    Sh[((och0 + r) * CHB + (rel + 1) * ROWU) * 2 + px + 4];
                const float xv = __uint_as_float(xr << 16);
                op[(och0 + r) * HW] = fmaf(d2[r], mfv, xv);
            }
        }
    }
#undef EXT3
}

extern "C" void kernel_launch(void* const* d_in, const int* in_sizes, int n_in,
                              void* d_out, int out_size, void* d_ws, size_t ws_size,
                              hipStream_t stream) {
    const float* x    = (const float*)d_in[0];
    const float* w1w  = (const float*)d_in[1];
    const float* w1b  = (const float*)d_in[2];
    const float* w2w  = (const float*)d_in[3];
    const int*   mask = (const int*)d_in[4];
    float* out = (float*)d_out;
    float* wdf = (float*)d_ws;            // 3.1 KB of fragment scratch

    hipLaunchKernelGGL(repack, dim3(1), dim3(64), 0, stream,
                       w1w, w1b, w2w, wdf);
    hipLaunchKernelGGL(nca_step_kernel, dim3(B * H / 2), dim3(512), 0, stream,
                       x, mask, out, wdf);
}

// Round 17
// 86.508 us; speedup vs baseline: 1.0004x; 1.0004x over previous
//
#include <hip/hip_runtime.h>
#include <hip/hip_bf16.h>
#include <stdint.h>

// Fused NCA step via MATRIX CORES — DS-pipe-minimized build.
// perception(4 fixed 3x3, wrap) -> 1x1 conv 32->16 +b+ReLU -> 1x1 conv 16->8
// -> x + y*mask.
// R17 = R14 (80.7us, best) with LDS-instruction cuts only; structure proven:
//  - residual x: 32 prologue global dword loads (L2-hot, rows just staged)
//    replace 32 epilogue ds_reads. Lanes>=32 duplicate lanes 0-31 addresses
//    (their och0 would be OOB; duplicates are coalesced & harmless).
//  - mask: 8 prologue global loads (no LDS mask region, no mask DMAs).
//  - full unroll (static msk[i]/xres[i][r] indexing, rule #20) + HW cvt_pk.
// DS ops/wave ~176 -> ~100; VMEM pipe absorbs the moved loads.

constexpr int B = 16, C = 8, H = 512, W = 512, HID = 16;
constexpr int HW = H * W;

// LDS geometry (floats). Rows halo-padded: [pad3][lhalo][512 data][rhalo]
// data col c at idx c+4; left halo idx3 = col 511; right halo idx516 = col 0.
constexpr int ROWF = 520;            // 2080 B, 16B-aligned rows
constexpr int CHF  = 4 * ROWF + 8;   // 2088: +8 pad spreads channels over banks
constexpr int LDSF = 8 * CHF;        // 16704 floats = 66816 B

typedef __attribute__((ext_vector_type(8))) short bf16x8;
typedef __attribute__((ext_vector_type(4))) float f32x4;
typedef const __attribute__((address_space(1))) void* as1cp;
typedef __attribute__((address_space(3))) void* as3p;

__device__ __host__ inline uint32_t bf16rne(float f) {   // result in low 16
    const uint32_t u = __float_as_uint(f);
    return (u + 0x7fffu + ((u >> 16) & 1u)) >> 16;
}
__device__ inline float bf16tof(uint32_t hs) { return __uint_as_float(hs << 16); }

// pack two floats to {bf16 lo, bf16 hi} via HW cvt_pk (RNE)
__device__ inline uint32_t pk2(float a, float b) {
    union { __hip_bfloat162 h; uint32_t u; } r;
    r.h = __float22bfloat162_rn(make_float2(a, b));
    return r.u;
}

// d_ws layout (u32 units):
//  [0..255]   W1eff hi A-frag: lane t holds elems j=0..7 of (row=t&15, grp=t>>4)
//  [256..511] W1eff lo A-frag
//  [512..767] W2 A-frag, K=32 zero-padded: j<4 -> w2[och=t&15][(t>>4)*4+j]
//             (0 for och>=8), j>=4 -> 0
//  [768..783] bias (f32)
__global__ void repack(const float* __restrict__ w1w,
                       const float* __restrict__ w1b,
                       const float* __restrict__ w2w,
                       float* __restrict__ wdf) {
    uint32_t* wd = (uint32_t*)wdf;
    const int t = threadIdx.x;
    if (t >= 64) return;
    const int h = t & 15, kg = t >> 4;
    uint32_t whi[4] = {0, 0, 0, 0}, wlo[4] = {0, 0, 0, 0}, w2f[4] = {0, 0, 0, 0};
    for (int j = 0; j < 8; ++j) {
        const int k = kg * 8 + j, ch = k >> 2, f = k & 3;
        const float* wr = w1w + h * 32 + ch * 4;
        // fold perception scales + lap's -ident into W1
        const float we = (f == 0) ? (wr[0] - wr[3])
                       : (f == 3) ? wr[3] * 0.0625f
                                  : wr[f] * 0.125f;
        const uint32_t hs = bf16rne(we);
        const uint32_t ls = bf16rne(we - bf16tof(hs));
        whi[j >> 1] |= hs << (16 * (j & 1));
        wlo[j >> 1] |= ls << (16 * (j & 1));
    }
    for (int j = 0; j < 4; ++j) {        // conv2 frag: j>=4 stays zero
        const float v = (h < 8) ? w2w[h * 16 + kg * 4 + j] : 0.0f;
        w2f[j >> 1] |= bf16rne(v) << (16 * (j & 1));
    }
    for (int q = 0; q < 4; ++q) {
        wd[t * 4 + q]       = whi[q];
        wd[256 + t * 4 + q] = wlo[q];
        wd[512 + t * 4 + q] = w2f[q];
    }
    if (t < 16) wdf[768 + t] = w1b[t];
}

__global__ __launch_bounds__(512, 4) void nca_step_kernel(
    const float* __restrict__ x,
    const int*   __restrict__ mask,
    float*       __restrict__ out,
    const float* __restrict__ wdf)
{
    __shared__ float S[LDSF];

    // block = one row PAIR; XCD-bijective swizzle (4096 = 8 * 512)
    const int bid = blockIdx.x;
    const int l   = (bid & 7) * 512 + (bid >> 3);
    const int b   = l >> 8;
    const int y0  = (l & 255) << 1;

    const int tid  = threadIdx.x;
    const int lane = tid & 63;
    const int wv   = tid >> 6;            // wave 0..7

    const float* xb = x + (size_t)b * C * HW;
    const int*   mb = mask + (size_t)b * HW;

    const int rel = wv >> 2;              // 0: row y0, 1: row y1
    const int y   = y0 + rel;
    const int grp = lane >> 4;            // lane-group: channels 2grp, 2grp+1
    const int p   = lane & 15;            // px within group
    const int chA = grp * 2;
    const int och0m = (grp & 1) * 4;      // epilogue och base (lanes>=32 dup)

    // ---- prologue global loads: mask + residual x (replace LDS reads) ----
    int msk[8];
#pragma unroll
    for (int i = 0; i < 8; ++i)
        msk[i] = mb[y * W + ((wv & 3) + 4 * i) * 16 + p];
    float xres[8][4];
#pragma unroll
    for (int i = 0; i < 8; ++i) {
        const int px = (((wv & 3) + 4 * i) * 16) + p;
#pragma unroll
        for (int r = 0; r < 4; ++r)
            xres[i][r] = xb[(och0m + r) * HW + y * W + px];
    }

    // per-lane constant fragments (same for every wave)
    union { uint4 u; bf16x8 v; } whiU, wloU, w2U;
    whiU.u = ((const uint4*)wdf)[lane];
    wloU.u = ((const uint4*)wdf)[64 + lane];
    w2U.u  = ((const uint4*)wdf)[128 + lane];
    const f32x4 bias4 = ((const f32x4*)(wdf + 768))[lane >> 4];

    // ---- stage: 8ch x 4 rows (y0-1..y0+2), 64 x 1KB DMAs, 8 per wave ----
    // wave wv owns (rs = (wv>>1)&3, hf = wv&1) for all 8 channels
    {
        const int rs   = (wv >> 1) & 3;
        const int hf   = wv & 1;
        const int grow = (y0 - 1 + rs) & (H - 1);
        const int goff = grow * W + hf * 256 + lane * 4;
        const int loff = rs * ROWF + 4 + hf * 256;
#pragma unroll
        for (int ch = 0; ch < 8; ++ch) {
            const float* src = xb + ch * HW + goff;
            float* dst = S + ch * CHF + loff;
            __builtin_amdgcn_global_load_lds((as1cp)src, (as3p)dst, 16, 0, 0);
        }
    }
    __syncthreads();                      // drains the DMAs
    if (tid < 64) {                       // halo fill (wrap columns)
        const int r = tid >> 1;
        float* rb = S + (r >> 2) * CHF + (r & 3) * ROWF;
        if (tid & 1) rb[516] = rb[4];     // right halo = col 0
        else         rb[3]   = rb[515];   // left halo  = col 511
    }
    __syncthreads();

    float* ob = out + (size_t)b * C * HW;

    // ---- compute: wave wv -> row y0+rel, px groups (wv&3)+4i ----
#pragma unroll
    for (int i = 0; i < 8; ++i) {
        const int g  = (wv & 3) + i * 4;
        const int px = g * 16 + p;
        const int ci = px + 3;            // LDS idx of col px-1

        // features in fragment element order: j=0..3 ch=chA, j=4..7 ch=chA+1,
        // each {ident, sx_raw, sy_raw, lap_raw} (scales folded into W1)
        float f_[8];
#pragma unroll
        for (int cc = 0; cc < 2; ++cc) {
            const float* R0 = S + (chA + cc) * CHF + rel * ROWF + ci;
            const float* R1 = R0 + ROWF;
            const float* R2 = R1 + ROWF;
            const float a0 = R0[0], a1 = R0[1], a2 = R0[2];
            const float b0 = R1[0], b1 = R1[1], b2 = R1[2];
            const float c0 = R2[0], c1 = R2[1], c2 = R2[2];
            const float s0 = fmaf(2.f, b0, a0 + c0);
            const float s1 = fmaf(2.f, b1, a1 + c1);
            const float s2 = fmaf(2.f, b2, a2 + c2);
            const float d0 = c0 - a0, d1 = c1 - a1, d2 = c2 - a2;
            f_[cc * 4 + 0] = b1;
            f_[cc * 4 + 1] = s2 - s0;
            f_[cc * 4 + 2] = fmaf(2.f, d1, d0 + d2);
            f_[cc * 4 + 3] = fmaf(2.f, s1, s0 + s2);
        }

        // single-bf16 feature fragment: 4x HW cvt_pk
        union { uint32_t u[4]; bf16x8 v; } bh = {{
            pk2(f_[0], f_[1]), pk2(f_[2], f_[3]),
            pk2(f_[4], f_[5]), pk2(f_[6], f_[7])}};

        // conv1: W*F = (Whi + Wlo)*F   (W split exact; bias preloaded in C)
        f32x4 acc = bias4;
        acc = __builtin_amdgcn_mfma_f32_16x16x32_bf16(whiU.v, bh.v, acc, 0, 0, 0);
        acc = __builtin_amdgcn_mfma_f32_16x16x32_bf16(wloU.v, bh.v, acc, 0, 0, 0);

        // conv2 via the SAME verified K=32 builtin, zero-padded fragments:
        // B elems j<4 = relu(acc[j]) (= hid 4*grp+j), j>=4 = 0; A likewise.
        union { uint32_t u[4]; bf16x8 v; } b2 = {{
            pk2(fmaxf(acc[0], 0.f), fmaxf(acc[1], 0.f)),
            pk2(fmaxf(acc[2], 0.f), fmaxf(acc[3], 0.f)), 0, 0}};
        f32x4 d2 = {0.f, 0.f, 0.f, 0.f};
        d2 = __builtin_amdgcn_mfma_f32_16x16x32_bf16(w2U.v, b2.v, d2, 0, 0, 0);

        // epilogue: lanes 0..31 hold och=(lane>>4)*4+r (rows 8..15 are pad)
        if (lane < 32) {
            const float mfv = (float)msk[i];
            float* op = ob + y * W + px;
#pragma unroll
            for (int r = 0; r < 4; ++r)
                op[(och0m + r) * HW] = fmaf(d2[r], mfv, xres[i][r]);
        }
    }
}

extern "C" void kernel_launch(void* const* d_in, const int* in_sizes, int n_in,
                              void* d_out, int out_size, void* d_ws, size_t ws_size,
                              hipStream_t stream) {
    const float* x    = (const float*)d_in[0];
    const float* w1w  = (const float*)d_in[1];
    const float* w1b  = (const float*)d_in[2];
    const float* w2w  = (const float*)d_in[3];
    const int*   mask = (const int*)d_in[4];
    float* out = (float*)d_out;
    float* wdf = (float*)d_ws;            // 3.1 KB of fragment scratch

    hipLaunchKernelGGL(repack, dim3(1), dim3(64), 0, stream,
                       w1w, w1b, w2w, wdf);
    hipLaunchKernelGGL(nca_step_kernel, dim3(B * H / 2), dim3(512), 0, stream,
                       x, mask, out, wdf);
}

// Round 18
// 84.495 us; speedup vs baseline: 1.0242x; 1.0238x over previous
//
#include <hip/hip_runtime.h>
#include <stdint.h>

// Fused NCA step via MATRIX CORES — split-stage pipelined build.
// perception(4 fixed 3x3, wrap) -> 1x1 conv 32->16 +b+ReLU -> 1x1 conv 16->8
// -> x + y*mask.
// R18 = R14 (80.7us best; compute body byte-identical) with the monolithic
// stage->barrier->compute replaced by column-half pipelining:
//   phase0: STAGE_L (cols 0..255, 32 DMAs + 2 mask DMAs) + 96 boundary
//           gloads (col 511->slot3, col 0->slot516, col 256->slot260;
//           slot260 is also written by STAGE_R with the SAME bytes - benign).
//   bar1 -> issue STAGE_R (cols 256..511) -> compute L groups (i=0..3)
//           while STAGE_R flies -> bar2 -> compute R groups (i=4..7).
// R15/R16/R17 showed VALU cuts / occupancy / DS cuts all regress; the
// remaining idle (VALUBusy~50% @ 2 blocks/CU) is stage/compute serialization.

constexpr int B = 16, C = 8, H = 512, W = 512, HID = 16;
constexpr int HW = H * W;

// LDS geometry (floats). Rows halo-padded: [pad3][lhalo][512 data][rhalo]
// data col c at idx c+4; left halo idx3 = col 511; right halo idx516 = col 0.
constexpr int ROWF = 520;            // 2080 B, 16B-aligned rows
constexpr int CHF  = 4 * ROWF + 8;   // 2088: +8 pad spreads channels over banks
constexpr int XTOT = 8 * CHF;        // 16704
constexpr int MOFF = XTOT;           // 2 mask rows (raw int bits)
constexpr int LDSF = XTOT + 2 * 512; // 17728 floats = 70912 B

typedef __attribute__((ext_vector_type(8))) short bf16x8;
typedef __attribute__((ext_vector_type(4))) float f32x4;
typedef const __attribute__((address_space(1))) void* as1cp;
typedef __attribute__((address_space(3))) void* as3p;

__device__ __host__ inline uint32_t bf16rne(float f) {   // result in low 16
    const uint32_t u = __float_as_uint(f);
    return (u + 0x7fffu + ((u >> 16) & 1u)) >> 16;
}
__device__ inline float bf16tof(uint32_t hs) { return __uint_as_float(hs << 16); }

// pack {bf16(a) lo, bf16(b) hi} : 2x(RNE round) + 1 v_perm_b32 (R14-proven)
__device__ inline uint32_t pkbf(float a, float b) {
    const uint32_t ua = __float_as_uint(a);
    const uint32_t ub = __float_as_uint(b);
    const uint32_t ra = ua + 0x7fffu + ((ua >> 16) & 1u);
    const uint32_t rb = ub + 0x7fffu + ((ub >> 16) & 1u);
    return __builtin_amdgcn_perm(rb, ra, 0x07060302u);   // {ra.hi16, rb.hi16}
}

// d_ws layout (u32 units):
//  [0..255]   W1eff hi A-frag: lane t holds elems j=0..7 of (row=t&15, grp=t>>4)
//  [256..511] W1eff lo A-frag
//  [512..767] W2 A-frag, K=32 zero-padded: j<4 -> w2[och=t&15][(t>>4)*4+j]
//             (0 for och>=8), j>=4 -> 0
//  [768..783] bias (f32)
__global__ void repack(const float* __restrict__ w1w,
                       const float* __restrict__ w1b,
                       const float* __restrict__ w2w,
                       float* __restrict__ wdf) {
    uint32_t* wd = (uint32_t*)wdf;
    const int t = threadIdx.x;
    if (t >= 64) return;
    const int h = t & 15, kg = t >> 4;
    uint32_t whi[4] = {0, 0, 0, 0}, wlo[4] = {0, 0, 0, 0}, w2f[4] = {0, 0, 0, 0};
    for (int j = 0; j < 8; ++j) {
        const int k = kg * 8 + j, ch = k >> 2, f = k & 3;
        const float* wr = w1w + h * 32 + ch * 4;
        // fold perception scales + lap's -ident into W1
        const float we = (f == 0) ? (wr[0] - wr[3])
                       : (f == 3) ? wr[3] * 0.0625f
                                  : wr[f] * 0.125f;
        const uint32_t hs = bf16rne(we);
        const uint32_t ls = bf16rne(we - bf16tof(hs));
        whi[j >> 1] |= hs << (16 * (j & 1));
        wlo[j >> 1] |= ls << (16 * (j & 1));
    }
    for (int j = 0; j < 4; ++j) {        // conv2 frag: j>=4 stays zero
        const float v = (h < 8) ? w2w[h * 16 + kg * 4 + j] : 0.0f;
        w2f[j >> 1] |= bf16rne(v) << (16 * (j & 1));
    }
    for (int q = 0; q < 4; ++q) {
        wd[t * 4 + q]       = whi[q];
        wd[256 + t * 4 + q] = wlo[q];
        wd[512 + t * 4 + q] = w2f[q];
    }
    if (t < 16) wdf[768 + t] = w1b[t];
}

__global__ __launch_bounds__(512, 4) void nca_step_kernel(
    const float* __restrict__ x,
    const int*   __restrict__ mask,
    float*       __restrict__ out,
    const float* __restrict__ wdf)
{
    __shared__ float S[LDSF];

    // block = one row PAIR; XCD-bijective swizzle (4096 = 8 * 512)
    const int bid = blockIdx.x;
    const int l   = (bid & 7) * 512 + (bid >> 3);
    const int b   = l >> 8;
    const int y0  = (l & 255) << 1;

    const int tid  = threadIdx.x;
    const int lane = tid & 63;
    const int wv   = tid >> 6;            // wave 0..7

    const float* xb = x + (size_t)b * C * HW;
    const int*   mb = mask + (size_t)b * HW;

    // per-wave stage geometry: wave wv stages row rs for 4 channels
    const int rs   = wv & 3;
    const int chW  = wv >> 2;             // ch parity: {0,2,4,6} or {1,3,5,7}
    const int grow = (y0 - 1 + rs) & (H - 1);

#define STAGE_HALF(hf) do {                                                \
    const int goff = grow * W + (hf) * 256 + lane * 4;                     \
    const int loff = rs * ROWF + 4 + (hf) * 256;                           \
    _Pragma("unroll") for (int cq = 0; cq < 4; ++cq) {                     \
        const int ch = chW + cq * 2;                                       \
        __builtin_amdgcn_global_load_lds((as1cp)(xb + ch * HW + goff),     \
                                         (as3p)(S + ch * CHF + loff),      \
                                         16, 0, 0);                        \
    }                                                                      \
    if (wv < 2) {                         /* mask rows y0,y1: 1 KB each */ \
        const int* msrc = mb + (y0 + wv) * W + (hf) * 256 + lane * 4;      \
        float* mdst = S + MOFF + wv * 512 + (hf) * 256;                    \
        __builtin_amdgcn_global_load_lds((as1cp)msrc, (as3p)mdst,          \
                                         16, 0, 0);                        \
    } } while (0)

    // ---- phase 0: stage left half + boundary columns from global ----
    STAGE_HALF(0);
    if (tid < 96) {                       // 96 boundary loads, 1 per thread
        const int set = tid >> 5;         // 0: col511->3, 1: col0->516, 2: col256->260
        const int r   = tid & 31;
        const int hch = r >> 2, hrs = r & 3;
        const int hrow = (y0 - 1 + hrs) & (H - 1);
        const int col  = (set == 0) ? 511 : ((set == 1) ? 0 : 256);
        const int slot = (set == 0) ? 3 : ((set == 1) ? 516 : 260);
        S[hch * CHF + hrs * ROWF + slot] = xb[hch * HW + hrow * W + col];
    }
    __syncthreads();                      // L half + boundaries visible

    // ---- phase 1: issue right half (flies during compute-L) ----
    STAGE_HALF(1);
#undef STAGE_HALF

    // per-lane constant fragments (same for every wave)
    union { uint4 u; bf16x8 v; } whiU, wloU, w2U;
    whiU.u = ((const uint4*)wdf)[lane];
    wloU.u = ((const uint4*)wdf)[64 + lane];
    w2U.u  = ((const uint4*)wdf)[128 + lane];
    const f32x4 bias4 = ((const f32x4*)(wdf + 768))[lane >> 4];

    const int rel = wv >> 2;              // 0: row y0, 1: row y1
    const int y   = y0 + rel;
    const int grp = lane >> 4;            // lane-group: channels 2grp, 2grp+1
    const int p   = lane & 15;            // px within group
    const int chA = grp * 2;
    float* ob = out + (size_t)b * C * HW;

    // compute body: byte-identical to R14
#define BODY(i) do {                                                       \
    const int g  = (wv & 3) + (i) * 4;                                     \
    const int px = g * 16 + p;                                             \
    const int ci = px + 3;            /* LDS idx of col px-1 */            \
    float f_[8];                                                           \
    _Pragma("unroll") for (int cc = 0; cc < 2; ++cc) {                     \
        const float* R0 = S + (chA + cc) * CHF + rel * ROWF + ci;          \
        const float* R1 = R0 + ROWF;                                       \
        const float* R2 = R1 + ROWF;                                       \
        const float a0 = R0[0], a1 = R0[1], a2 = R0[2];                    \
        const float b0 = R1[0], b1 = R1[1], b2 = R1[2];                    \
        const float c0 = R2[0], c1 = R2[1], c2 = R2[2];                    \
        const float s0 = fmaf(2.f, b0, a0 + c0);                           \
        const float s1 = fmaf(2.f, b1, a1 + c1);                           \
        const float s2 = fmaf(2.f, b2, a2 + c2);                           \
        const float d0 = c0 - a0, d1 = c1 - a1, d2 = c2 - a2;              \
        f_[cc * 4 + 0] = b1;                                               \
        f_[cc * 4 + 1] = s2 - s0;                                          \
        f_[cc * 4 + 2] = fmaf(2.f, d1, d0 + d2);                           \
        f_[cc * 4 + 3] = fmaf(2.f, s1, s0 + s2); }                         \
    union { uint32_t u[4]; bf16x8 v; } bh = {{                             \
        pkbf(f_[0], f_[1]), pkbf(f_[2], f_[3]),                            \
        pkbf(f_[4], f_[5]), pkbf(f_[6], f_[7])}};                          \
    f32x4 acc = bias4;                                                     \
    acc = __builtin_amdgcn_mfma_f32_16x16x32_bf16(whiU.v, bh.v, acc, 0, 0, 0); \
    acc = __builtin_amdgcn_mfma_f32_16x16x32_bf16(wloU.v, bh.v, acc, 0, 0, 0); \
    union { uint32_t u[4]; bf16x8 v; } b2 = {{                             \
        pkbf(fmaxf(acc[0], 0.f), fmaxf(acc[1], 0.f)),                      \
        pkbf(fmaxf(acc[2], 0.f), fmaxf(acc[3], 0.f)), 0, 0}};              \
    f32x4 d2 = {0.f, 0.f, 0.f, 0.f};                                       \
    d2 = __builtin_amdgcn_mfma_f32_16x16x32_bf16(w2U.v, b2.v, d2, 0, 0, 0); \
    if (lane < 32) {                                                       \
        const float mfv = (float)((const int*)(S + MOFF))[rel * 512 + px]; \
        const int och0 = grp * 4;                                          \
        float* op = ob + y * W + px;                                       \
        _Pragma("unroll") for (int r = 0; r < 4; ++r) {                    \
            const float xv = S[(och0 + r) * CHF + (rel + 1) * ROWF + 4 + px]; \
            op[(och0 + r) * HW] = fmaf(d2[r], mfv, xv); } } } while (0)

    // ---- compute L groups (px 0..255) while STAGE_R is in flight ----
#pragma unroll 2
    for (int i = 0; i < 4; ++i) BODY(i);

    __syncthreads();                      // drains STAGE_R

    // ---- compute R groups (px 256..511) ----
#pragma unroll 2
    for (int i = 4; i < 8; ++i) BODY(i);
#undef BODY
}

extern "C" void kernel_launch(void* const* d_in, const int* in_sizes, int n_in,
                              void* d_out, int out_size, void* d_ws, size_t ws_size,
                              hipStream_t stream) {
    const float* x    = (const float*)d_in[0];
    const float* w1w  = (const float*)d_in[1];
    const float* w1b  = (const float*)d_in[2];
    const float* w2w  = (const float*)d_in[3];
    const int*   mask = (const int*)d_in[4];
    float* out = (float*)d_out;
    float* wdf = (float*)d_ws;            // 3.1 KB of fragment scratch

    hipLaunchKernelGGL(repack, dim3(1), dim3(64), 0, stream,
                       w1w, w1b, w2w, wdf);
    hipLaunchKernelGGL(nca_step_kernel, dim3(B * H / 2), dim3(512), 0, stream,
                       x, mask, out, wdf);
}

// Round 19
// 80.738 us; speedup vs baseline: 1.0719x; 1.0465x over previous
//
#include <hip/hip_runtime.h>
#include <stdint.h>

// Fused NCA step via MATRIX CORES — max-wave build.
// perception(4 fixed 3x3, wrap) -> 1x1 conv 32->16 +b+ReLU -> 1x1 conv 16->8
// -> x + y*mask.
// R19 = R14 (80.7us best) with ONE change: 1024-thread blocks. Same 71KB
// LDS tile now serves 16 waves instead of 8 -> 2 blocks/CU = 32 waves/CU
// (hardware max, was 16). Each wave: 4 iters (was 8). This is R16's
// occupancy doubling WITHOUT its bf16-extract VALU tax. Per-iter body,
// LDS layout, fragments, numerics byte-identical to R14.

constexpr int B = 16, C = 8, H = 512, W = 512, HID = 16;
constexpr int HW = H * W;

// LDS geometry (floats). Rows halo-padded: [pad3][lhalo][512 data][rhalo]
// data col c at idx c+4; left halo idx3 = col 511; right halo idx516 = col 0.
constexpr int ROWF = 520;            // 2080 B, 16B-aligned rows
constexpr int CHF  = 4 * ROWF + 8;   // 2088: +8 pad spreads channels over banks
constexpr int XTOT = 8 * CHF;        // 16704
constexpr int MOFF = XTOT;           // 2 mask rows (raw int bits)
constexpr int LDSF = XTOT + 2 * 512; // 17728 floats = 70912 B

typedef __attribute__((ext_vector_type(8))) short bf16x8;
typedef __attribute__((ext_vector_type(4))) float f32x4;
typedef const __attribute__((address_space(1))) void* as1cp;
typedef __attribute__((address_space(3))) void* as3p;

__device__ __host__ inline uint32_t bf16rne(float f) {   // result in low 16
    const uint32_t u = __float_as_uint(f);
    return (u + 0x7fffu + ((u >> 16) & 1u)) >> 16;
}
__device__ inline float bf16tof(uint32_t hs) { return __uint_as_float(hs << 16); }

// pack {bf16(a) lo, bf16(b) hi} : 2x(RNE round) + 1 v_perm_b32 (R14-proven)
__device__ inline uint32_t pkbf(float a, float b) {
    const uint32_t ua = __float_as_uint(a);
    const uint32_t ub = __float_as_uint(b);
    const uint32_t ra = ua + 0x7fffu + ((ua >> 16) & 1u);
    const uint32_t rb = ub + 0x7fffu + ((ub >> 16) & 1u);
    return __builtin_amdgcn_perm(rb, ra, 0x07060302u);   // {ra.hi16, rb.hi16}
}

// d_ws layout (u32 units):
//  [0..255]   W1eff hi A-frag: lane t holds elems j=0..7 of (row=t&15, grp=t>>4)
//  [256..511] W1eff lo A-frag
//  [512..767] W2 A-frag, K=32 zero-padded: j<4 -> w2[och=t&15][(t>>4)*4+j]
//             (0 for och>=8), j>=4 -> 0
//  [768..783] bias (f32)
__global__ void repack(const float* __restrict__ w1w,
                       const float* __restrict__ w1b,
                       const float* __restrict__ w2w,
                       float* __restrict__ wdf) {
    uint32_t* wd = (uint32_t*)wdf;
    const int t = threadIdx.x;
    if (t >= 64) return;
    const int h = t & 15, kg = t >> 4;
    uint32_t whi[4] = {0, 0, 0, 0}, wlo[4] = {0, 0, 0, 0}, w2f[4] = {0, 0, 0, 0};
    for (int j = 0; j < 8; ++j) {
        const int k = kg * 8 + j, ch = k >> 2, f = k & 3;
        const float* wr = w1w + h * 32 + ch * 4;
        // fold perception scales + lap's -ident into W1
        const float we = (f == 0) ? (wr[0] - wr[3])
                       : (f == 3) ? wr[3] * 0.0625f
                                  : wr[f] * 0.125f;
        const uint32_t hs = bf16rne(we);
        const uint32_t ls = bf16rne(we - bf16tof(hs));
        whi[j >> 1] |= hs << (16 * (j & 1));
        wlo[j >> 1] |= ls << (16 * (j & 1));
    }
    for (int j = 0; j < 4; ++j) {        // conv2 frag: j>=4 stays zero
        const float v = (h < 8) ? w2w[h * 16 + kg * 4 + j] : 0.0f;
        w2f[j >> 1] |= bf16rne(v) << (16 * (j & 1));
    }
    for (int q = 0; q < 4; ++q) {
        wd[t * 4 + q]       = whi[q];
        wd[256 + t * 4 + q] = wlo[q];
        wd[512 + t * 4 + q] = w2f[q];
    }
    if (t < 16) wdf[768 + t] = w1b[t];
}

__global__ __launch_bounds__(1024, 8) void nca_step_kernel(
    const float* __restrict__ x,
    const int*   __restrict__ mask,
    float*       __restrict__ out,
    const float* __restrict__ wdf)
{
    __shared__ float S[LDSF];

    // block = one row PAIR; XCD-bijective swizzle (4096 = 8 * 512)
    const int bid = blockIdx.x;
    const int l   = (bid & 7) * 512 + (bid >> 3);
    const int b   = l >> 8;
    const int y0  = (l & 255) << 1;

    const int tid  = threadIdx.x;
    const int lane = tid & 63;
    const int wv   = tid >> 6;            // wave 0..15

    const float* xb = x + (size_t)b * C * HW;
    const int*   mb = mask + (size_t)b * HW;

    // per-lane constant fragments (same for every wave)
    union { uint4 u; bf16x8 v; } whiU, wloU, w2U;
    whiU.u = ((const uint4*)wdf)[lane];
    wloU.u = ((const uint4*)wdf)[64 + lane];
    w2U.u  = ((const uint4*)wdf)[128 + lane];
    const f32x4 bias4 = ((const f32x4*)(wdf + 768))[lane >> 4];

    // ---- stage: 64 x-chunks (8ch x 4rows x 2halves) = 4 DMAs/wave ----
    // wave wv: channel wv>>1, rows (wv&1)*2 .. +1, both halves. Uniform.
    {
        const int ch  = wv >> 1;
        const int rs0 = (wv & 1) * 2;
#pragma unroll
        for (int j = 0; j < 4; ++j) {
            const int rs = rs0 + (j >> 1);
            const int hf = j & 1;
            const int grow = (y0 - 1 + rs) & (H - 1);
            const float* src = xb + ch * HW + grow * W + hf * 256 + lane * 4;
            float* dst = S + ch * CHF + rs * ROWF + 4 + hf * 256;
            __builtin_amdgcn_global_load_lds((as1cp)src, (as3p)dst, 16, 0, 0);
        }
        if (wv < 4) {                     // 4 mask chunks (2 rows x 2 halves)
            const int mr = wv >> 1, hf = wv & 1;
            const int* msrc = mb + (y0 + mr) * W + hf * 256 + lane * 4;
            float* mdst = S + MOFF + mr * 512 + hf * 256;
            __builtin_amdgcn_global_load_lds((as1cp)msrc, (as3p)mdst, 16, 0, 0);
        }
    }
    __syncthreads();                      // drains the DMAs
    if (tid < 64) {                       // halo fill (wrap columns)
        const int r = tid >> 1;
        float* rb = S + (r >> 2) * CHF + (r & 3) * ROWF;
        if (tid & 1) rb[516] = rb[4];     // right halo = col 0
        else         rb[3]   = rb[515];   // left halo  = col 511
    }
    __syncthreads();

    // ---- compute: wave wv -> row y0+(wv>>3), groups (wv&7)+8i, i=0..3 ----
    const int rel = wv >> 3;
    const int y   = y0 + rel;
    const int grp = lane >> 4;            // lane-group: channels 2grp, 2grp+1
    const int p   = lane & 15;            // px within group
    const int chA = grp * 2;
    float* ob = out + (size_t)b * C * HW;

#pragma unroll 2
    for (int i = 0; i < 4; ++i) {
        const int g  = (wv & 7) + i * 8;
        const int px = g * 16 + p;
        const int ci = px + 3;            // LDS idx of col px-1

        // features in fragment element order: j=0..3 ch=chA, j=4..7 ch=chA+1,
        // each {ident, sx_raw, sy_raw, lap_raw} (scales folded into W1)
        float f_[8];
#pragma unroll
        for (int cc = 0; cc < 2; ++cc) {
            const float* R0 = S + (chA + cc) * CHF + rel * ROWF + ci;
            const float* R1 = R0 + ROWF;
            const float* R2 = R1 + ROWF;
            const float a0 = R0[0], a1 = R0[1], a2 = R0[2];
            const float b0 = R1[0], b1 = R1[1], b2 = R1[2];
            const float c0 = R2[0], c1 = R2[1], c2 = R2[2];
            const float s0 = fmaf(2.f, b0, a0 + c0);
            const float s1 = fmaf(2.f, b1, a1 + c1);
            const float s2 = fmaf(2.f, b2, a2 + c2);
            const float d0 = c0 - a0, d1 = c1 - a1, d2 = c2 - a2;
            f_[cc * 4 + 0] = b1;
            f_[cc * 4 + 1] = s2 - s0;
            f_[cc * 4 + 2] = fmaf(2.f, d1, d0 + d2);
            f_[cc * 4 + 3] = fmaf(2.f, s1, s0 + s2);
        }

        // single-bf16 feature fragment: 4x pkbf (RNE + v_perm)
        union { uint32_t u[4]; bf16x8 v; } bh = {{
            pkbf(f_[0], f_[1]), pkbf(f_[2], f_[3]),
            pkbf(f_[4], f_[5]), pkbf(f_[6], f_[7])}};

        // conv1: W*F = (Whi + Wlo)*F   (W split exact; bias preloaded in C)
        f32x4 acc = bias4;
        acc = __builtin_amdgcn_mfma_f32_16x16x32_bf16(whiU.v, bh.v, acc, 0, 0, 0);
        acc = __builtin_amdgcn_mfma_f32_16x16x32_bf16(wloU.v, bh.v, acc, 0, 0, 0);

        // conv2 via the SAME verified K=32 builtin, zero-padded fragments:
        // B elems j<4 = relu(acc[j]) (= hid 4*grp+j), j>=4 = 0; A likewise.
        union { uint32_t u[4]; bf16x8 v; } b2 = {{
            pkbf(fmaxf(acc[0], 0.f), fmaxf(acc[1], 0.f)),
            pkbf(fmaxf(acc[2], 0.f), fmaxf(acc[3], 0.f)), 0, 0}};
        f32x4 d2 = {0.f, 0.f, 0.f, 0.f};
        d2 = __builtin_amdgcn_mfma_f32_16x16x32_bf16(w2U.v, b2.v, d2, 0, 0, 0);

        // epilogue: lanes 0..31 hold och=(lane>>4)*4+r (rows 8..15 are pad)
        if (lane < 32) {
            const float mfv =
                (float)((const int*)(S + MOFF))[rel * 512 + px];
            const int och0 = grp * 4;
            float* op = ob + y * W + px;
#pragma unroll
            for (int r = 0; r < 4; ++r) {
                const float xv =
                    S[(och0 + r) * CHF + (rel + 1) * ROWF + 4 + px];
                op[(och0 + r) * HW] = fmaf(d2[r], mfv, xv);
            }
        }
    }
}

extern "C" void kernel_launch(void* const* d_in, const int* in_sizes, int n_in,
                              void* d_out, int out_size, void* d_ws, size_t ws_size,
                              hipStream_t stream) {
    const float* x    = (const float*)d_in[0];
    const float* w1w  = (const float*)d_in[1];
    const float* w1b  = (const float*)d_in[2];
    const float* w2w  = (const float*)d_in[3];
    const int*   mask = (const int*)d_in[4];
    float* out = (float*)d_out;
    float* wdf = (float*)d_ws;            // 3.1 KB of fragment scratch

    hipLaunchKernelGGL(repack, dim3(1), dim3(64), 0, stream,
                       w1w, w1b, w2w, wdf);
    hipLaunchKernelGGL(nca_step_kernel, dim3(B * H / 2), dim3(1024), 0, stream,
                       x, mask, out, wdf);
}